// Round 5
// baseline (346.293 us; speedup 1.0000x reference)
//
#include <hip/hip_runtime.h>
#include <hip/hip_bf16.h>

// ---------------------------------------------------------------------------
// OptimizedAttention R5: fused QKV proj (bf16 MFMA GEMM) -> K-RoPE ->
// causal GQA flash attention (128q blocks, key-range SPLIT-2 for heavy
// q-blocks + bf16 partial-O combine pass, LDS K/V dbuf staging, fixed-base
// exp2 softmax, mask-free fast path, Q-RoPE fused, XCD swizzle) -> out proj.
// R5 rationale: R4 grid was exactly CU capacity (4 blocks/CU) with 2..32-step
// block durations -> no queue, giant drain tail (OccupancyPercent 18%).
// Split-2 caps blocks at 16 steps and oversubscribes 6/CU vs 4 capacity.
// B=2 S=2048 H=2048 NH=32 NKV=8 DH=64 N_REP=4 THETA=1e4
// ---------------------------------------------------------------------------

using bf16 = __hip_bfloat16;
typedef __attribute__((ext_vector_type(8))) __bf16 bf8v;   // MFMA A/B frag (4 VGPR)
typedef __attribute__((ext_vector_type(4))) float  f4v;    // MFMA C/D frag

#define AS1 __attribute__((address_space(1)))
#define AS3 __attribute__((address_space(3)))

constexpr int cB = 2, cS = 2048, cH = 2048, cNH = 32, cNKV = 8, cDH = 64;
constexpr int cQKVW = 3072;   // fused QKV row width (2048 Q + 512 K + 512 V)

__device__ __forceinline__ void async_cp16(const bf16* g, bf16* l) {
    __builtin_amdgcn_global_load_lds((const AS1 unsigned int*)(const void*)g,
                                     (AS3 unsigned int*)(void*)l, 16, 0, 0);
}

__device__ __forceinline__ f4v mfma_16x16x32(bf8v a, bf8v b, f4v c) {
    return __builtin_amdgcn_mfma_f32_16x16x32_bf16(a, b, c, 0, 0, 0);
}

__device__ __forceinline__ void store_out(float* p, float v) { *p = v; }
__device__ __forceinline__ void store_out(bf16*  p, float v) { *p = __float2bfloat16(v); }

// ---------------------------------------------------------------------------
__global__ void cvt_f32_bf16(const float* __restrict__ in, bf16* __restrict__ outp, int n4) {
    int i = blockIdx.x * 256 + threadIdx.x;
    if (i >= n4) return;
    float4 v = ((const float4*)in)[i];
    union { bf16 h[4]; uint2 u; } p;
    p.h[0] = __float2bfloat16(v.x);
    p.h[1] = __float2bfloat16(v.y);
    p.h[2] = __float2bfloat16(v.z);
    p.h[3] = __float2bfloat16(v.w);
    ((uint2*)outp)[i] = p.u;
}

// fp32 [R][C] -> bf16 [C][R] transpose-convert (weights -> B^T layout)
__global__ void transpose_f32_bf16(const float* __restrict__ in, bf16* __restrict__ outp,
                                   int R, int C) {
    __shared__ float tile[32][33];
    int c0 = blockIdx.x * 32, r0 = blockIdx.y * 32;
    int tx = threadIdx.x, ty = threadIdx.y;
    for (int i = ty; i < 32; i += 8)
        tile[i][tx] = in[(long)(r0 + i) * C + c0 + tx];
    __syncthreads();
    for (int i = ty; i < 32; i += 8)
        outp[(long)(c0 + i) * R + r0 + tx] = __float2bfloat16(tile[tx][i]);
}

// V slice of QKV [tok][3072] (cols 2560..3071) -> VT [B][NKV][DH][S]
__global__ void transpose_v(const bf16* __restrict__ Vsrc, bf16* __restrict__ VT) {
    __shared__ float tile[32][33];
    int z = blockIdx.z;               // b*NKV + kv
    int b = z >> 3, kv = z & 7;
    int d0 = blockIdx.x * 32, s0 = blockIdx.y * 32;
    int tx = threadIdx.x, ty = threadIdx.y;
    for (int i = ty; i < 32; i += 8)
        tile[i][tx] = __bfloat162float(Vsrc[(long)(b * cS + s0 + i) * cQKVW + kv * cDH + d0 + tx]);
    __syncthreads();
    for (int i = ty; i < 32; i += 8)
        VT[((long)(b * cNKV + kv) * cDH + d0 + i) * cS + s0 + tx] = __float2bfloat16(tile[tx][i]);
}

// In-place RoPE on bf16 rows of stride `rowstride`; pair (d, d+32), d<32.
__global__ void rope_kernel(bf16* __restrict__ X, const int* __restrict__ pos,
                            int nh, int hshift, int rowstride, int total) {
    int idx = blockIdx.x * 256 + threadIdx.x;
    if (idx >= total) return;
    int d   = idx & 31;
    int t2  = idx >> 5;
    int hh  = t2 & (nh - 1);
    int tok = t2 >> hshift;
    float p   = (float)pos[tok];
    float inv = __expf(-(float)(2 * d) * (1.0f / 64.0f) * 9.210340371976184f);
    float ang = p * inv;
    float s = sinf(ang), c = cosf(ang);
    long base = (long)tok * rowstride + hh * 64 + d;
    float x1 = __bfloat162float(X[base]);
    float x2 = __bfloat162float(X[base + 32]);
    X[base]      = __float2bfloat16(x1 * c - x2 * s);
    X[base + 32] = __float2bfloat16(x2 * c + x1 * s);
}

// ---------------------------------------------------------------------------
// bf16 GEMM, B-transposed: C[M][N] = A[M][K] * BT[N][K]^T  (m97 structure)
// ---------------------------------------------------------------------------
template <typename OutT>
__global__ __launch_bounds__(256)
void gemm_bt(const bf16* __restrict__ A, const bf16* __restrict__ BT,
             OutT* __restrict__ C, int M, int N, int K) {
    __shared__ __align__(16) bf16 As[128 * 32];
    __shared__ __align__(16) bf16 Bs[128 * 32];
    const int tid  = threadIdx.x;
    const int lane = tid & 63;
    const int wave = tid >> 6;
    const int bm = blockIdx.x * 128;
    const int bn = blockIdx.y * 128;
    const int srow = tid >> 2;
    const int sch  = tid & 3;
    const int wm = (wave >> 1) * 64;
    const int wn = (wave & 1) * 64;
    const int lm = lane & 15;
    const int lq = lane >> 4;

    f4v acc[4][4];
    for (int i = 0; i < 4; ++i)
        for (int j = 0; j < 4; ++j)
            for (int r = 0; r < 4; ++r) acc[i][j][r] = 0.f;

    const bf16* aP0 = A  + (long)(bm + srow) * K      + sch * 8;
    const bf16* aP1 = A  + (long)(bm + 64 + srow) * K + sch * 8;
    const bf16* bP0 = BT + (long)(bn + srow) * K      + sch * 8;
    const bf16* bP1 = BT + (long)(bn + 64 + srow) * K + sch * 8;
    bf16* lA0 = &As[srow * 32 + sch * 8];
    bf16* lA1 = &As[(64 + srow) * 32 + sch * 8];
    bf16* lB0 = &Bs[srow * 32 + sch * 8];
    bf16* lB1 = &Bs[(64 + srow) * 32 + sch * 8];

    for (int k0 = 0; k0 < K; k0 += 32) {
        async_cp16(aP0 + k0, lA0);
        async_cp16(aP1 + k0, lA1);
        async_cp16(bP0 + k0, lB0);
        async_cp16(bP1 + k0, lB1);
        __syncthreads();

        bf8v af[4], bf_[4];
        for (int i = 0; i < 4; ++i)
            af[i]  = *(const bf8v*)&As[(wm + i * 16 + lm) * 32 + lq * 8];
        for (int j = 0; j < 4; ++j)
            bf_[j] = *(const bf8v*)&Bs[(wn + j * 16 + lm) * 32 + lq * 8];
        for (int i = 0; i < 4; ++i)
            for (int j = 0; j < 4; ++j)
                acc[i][j] = mfma_16x16x32(af[i], bf_[j], acc[i][j]);
        __syncthreads();
    }

    for (int i = 0; i < 4; ++i) {
        int row = bm + wm + i * 16 + lq * 4;
        for (int j = 0; j < 4; ++j) {
            int col = bn + wn + j * 16 + lm;
            for (int r = 0; r < 4; ++r)
                store_out(&C[(long)(row + r) * N + col], acc[i][j][r]);
        }
    }
}

// ---------------------------------------------------------------------------
// Causal GQA flash attention with key-range split.
// Block = 128 queries x key-range unit (24 units per (b,h), table-ordered
// heavy-first). Direct units (qblk 0..7) normalize and write O. Split units
// (qblk 8..15, two key halves each, <=16 steps) write unnormalized bf16
// partial O + fp32 l to Pbuf/Lbuf; attn_combine merges them.
// ---------------------------------------------------------------------------
__device__ const int g_qblk[24] = {7,15,15,14,14,6,13,13,12,12,5,11,11,10,10,4,9,9,8,8,3,2,1,0};
__device__ const int g_s0[24]   = {0,0,16,0,15,0,0,14,0,13,0,0,12,0,11,0,0,10,0,9,0,0,0,0};
__device__ const int g_s1[24]   = {16,16,32,15,30,14,14,28,13,26,12,12,24,11,22,10,10,20,9,18,8,6,4,2};
__device__ const int g_pidx[24] = {-1,14,15,12,13,-1,10,11,8,9,-1,6,7,4,5,-1,2,3,0,1,-1,-1,-1,-1};

__global__ __launch_bounds__(256)
void attn_kernel(const bf16* __restrict__ QKV, const bf16* __restrict__ VT,
                 const int* __restrict__ pos, bf16* __restrict__ O,
                 bf16* __restrict__ Pbuf, float* __restrict__ Lbuf) {
    __shared__ __align__(16) bf16 Kl[2][64 * 64];   // [buf][key][dh]   8KB x2
    __shared__ __align__(16) bf16 Vl[2][64 * 64];   // [buf][d][key]    8KB x2
    __shared__ __align__(16) bf16 Pl[4][16 * 64];   // per-wave P tile  2KB x4
    const int tid  = threadIdx.x;
    const int wave = tid >> 6, lane = tid & 63;
    const int lm = lane & 15, lq = lane >> 4;
    // block swizzle: idx = ord*64 + rep*16 + (b*8 + kvh); ord = unit table row
    const int idx = blockIdx.x;
    const int ord = idx >> 6;                       // 0..23, heavy-first
    const int bh2 = idx & 15;
    const int rep = (idx >> 4) & 3;
    const int b = bh2 >> 3, kvh = bh2 & 7;
    const int h = kvh * 4 + rep;
    const int qblk = g_qblk[ord];
    const int s0 = g_s0[ord], s1 = g_s1[ord];
    const int pidx = g_pidx[ord];
    const int q0 = qblk * 128;
    const int qw = q0 + wave * 32;                  // this wave's 32 queries

    // ---- Q fragments (B-frag: n=q=lm, k=dh=lq*8+j), RoPE + scale fused ----
    // SCALE = (1/sqrt(DH)) / ln(2): exp(s/8) == exp2(s_pre)
    constexpr float SCALE = 0.18033688011112042f;
    bf8v qf[2][2];
    for (int u = 0; u < 2; ++u) {
        const int qi = qw + u * 16 + lm;
        const bf16* qrow = QKV + (long)(b * cS + qi) * cQKVW + h * cDH;
        float p = (float)pos[b * cS + qi];
        bf8v r0 = *(const bf8v*)(qrow + lq * 8);
        bf8v r1 = *(const bf8v*)(qrow + 32 + lq * 8);
        bf8v t0, t1;
        for (int j = 0; j < 8; ++j) {
            int d = lq * 8 + j;
            float inv = __expf(-(float)(2 * d) * (1.0f / 64.0f) * 9.210340371976184f);
            float sn, cs;
            __sincosf(p * inv, &sn, &cs);
            float a = (float)r0[j], c2 = (float)r1[j];
            t0[j] = (__bf16)((a * cs - c2 * sn) * SCALE);
            t1[j] = (__bf16)((c2 * cs + a * sn) * SCALE);
        }
        qf[u][0] = t0; qf[u][1] = t1;
    }

    float lrow[2] = {0.f, 0.f};
    f4v o[2][4];
    for (int u = 0; u < 2; ++u)
        for (int t = 0; t < 4; ++t)
            for (int r = 0; r < 4; ++r) o[u][t][r] = 0.f;

    // P-tile swizzled addresses (wave-private, reused for both u)
    bf16* pw = &Pl[wave][0];
    const int x7 = lm & 7;
    int wr_addr[4], rd_addr[2];
    for (int t = 0; t < 4; ++t)
        wr_addr[t] = lm * 64 + (((t * 2 + (lq >> 1)) ^ x7) * 8) + (lq & 1) * 4;
    for (int c = 0; c < 2; ++c)
        rd_addr[c] = lm * 64 + (((c * 4 + lq) ^ x7) * 8);

    // staging: 256 threads cover 64 rows x 8 chunks(16B); source chunk index
    // XOR-swizzled by row so ds_read_b128 frag reads are conflict-free.
    const int srow = tid >> 3, sch = tid & 7;
    const bf16* kgb = QKV + (long)b * cS * cQKVW + 2048 + kvh * cDH;
    const bf16* vgb = VT + (long)(b * cNKV + kvh) * cDH * cS;
    auto stage = [&](int buf, int j0) {
        for (int i = 0; i < 2; ++i) {
            int row = i * 32 + srow;
            int sc8 = (sch ^ (row & 7)) * 8;
            async_cp16(kgb + (long)(j0 + row) * cQKVW + sc8, &Kl[buf][i * 2048 + tid * 8]);
            async_cp16(vgb + (long)row * cS + j0 + sc8,      &Vl[buf][i * 2048 + tid * 8]);
        }
    };

    stage(s0 & 1, s0 * 64);
    for (int step = s0; step < s1; ++step) {
        const int j0 = step * 64;
        const int cur = step & 1;
        if (step + 1 < s1) {
            stage(cur ^ 1, j0 + 64);
            asm volatile("s_waitcnt vmcnt(4)" ::: "memory");  // wait current tile only
        } else {
            asm volatile("s_waitcnt vmcnt(0)" ::: "memory");
        }
        asm volatile("s_barrier" ::: "memory");

        if (qw + 31 >= j0) {   // wave-uniform; skip fully-masked steps
            // ---- S^T = K . Q^T : A-frag = K[key][dh] from LDS ----
            f4v st[2][4];
            for (int u = 0; u < 2; ++u)
                for (int t = 0; t < 4; ++t)
                    for (int r = 0; r < 4; ++r) st[u][t][r] = 0.f;
            for (int t = 0; t < 4; ++t) {
                int kr = t * 16 + lm;
                bf8v kf0 = *(const bf8v*)&Kl[cur][kr * 64 + ((lq ^ (kr & 7)) * 8)];
                bf8v kf1 = *(const bf8v*)&Kl[cur][kr * 64 + (((4 + lq) ^ (kr & 7)) * 8)];
                for (int u = 0; u < 2; ++u) {
                    st[u][t] = mfma_16x16x32(kf0, qf[u][0], st[u][t]);
                    st[u][t] = mfma_16x16x32(kf1, qf[u][1], st[u][t]);
                }
            }
            // ---- V^T frags (A-frag: m=d, k=key), issued early ----
            bf8v vf[4][2];
            for (int t = 0; t < 4; ++t) {
                int vr = t * 16 + lm;
                vf[t][0] = *(const bf8v*)&Vl[cur][vr * 64 + ((lq ^ (vr & 7)) * 8)];
                vf[t][1] = *(const bf8v*)&Vl[cur][vr * 64 + (((4 + lq) ^ (vr & 7)) * 8)];
            }
            // ---- fixed-base softmax (bare exp2) + PV per u ----
            const bool boundary = (j0 + 63 > qw);   // wave-uniform
            for (int u = 0; u < 2; ++u) {
                float part = 0.f;
                if (boundary) {
                    const int qi = qw + u * 16 + lm;
                    for (int t = 0; t < 4; ++t)
                        for (int r = 0; r < 4; ++r) {
                            int key = j0 + t * 16 + lq * 4 + r;
                            float pv = (key <= qi) ? exp2f(st[u][t][r]) : 0.f;
                            st[u][t][r] = pv;
                            part += pv;
                        }
                } else {
                    for (int t = 0; t < 4; ++t)
                        for (int r = 0; r < 4; ++r) {
                            float pv = exp2f(st[u][t][r]);
                            st[u][t][r] = pv;
                            part += pv;
                        }
                }
                lrow[u] += part;
                for (int t = 0; t < 4; ++t) {
                    union { bf16 h4[4]; uint2 v; } pk;
                    pk.h4[0] = __float2bfloat16(st[u][t][0]);
                    pk.h4[1] = __float2bfloat16(st[u][t][1]);
                    pk.h4[2] = __float2bfloat16(st[u][t][2]);
                    pk.h4[3] = __float2bfloat16(st[u][t][3]);
                    *(uint2*)&pw[wr_addr[t]] = pk.v;
                }
                asm volatile("s_waitcnt lgkmcnt(0)" ::: "memory");
                bf8v pb0 = *(const bf8v*)&pw[rd_addr[0]];
                bf8v pb1 = *(const bf8v*)&pw[rd_addr[1]];
                for (int t = 0; t < 4; ++t) {
                    o[u][t] = mfma_16x16x32(vf[t][0], pb0, o[u][t]);
                    o[u][t] = mfma_16x16x32(vf[t][1], pb1, o[u][t]);
                }
            }
        }
        asm volatile("s_barrier" ::: "memory");   // reads done -> next stage may overwrite
    }

    // ---- epilogue ----
    if (pidx < 0) {
        // direct: normalize and write O[b][q][h][d]
        for (int u = 0; u < 2; ++u) {
            lrow[u] += __shfl_xor(lrow[u], 16);
            lrow[u] += __shfl_xor(lrow[u], 32);
            float inv = 1.0f / lrow[u];
            const int qi = qw + u * 16 + lm;
            bf16* orow = O + ((long)(b * cS + qi) * cNH + h) * cDH;
            for (int t = 0; t < 4; ++t) {
                union { bf16 h4[4]; uint2 v; } pk;
                pk.h4[0] = __float2bfloat16(o[u][t][0] * inv);
                pk.h4[1] = __float2bfloat16(o[u][t][1] * inv);
                pk.h4[2] = __float2bfloat16(o[u][t][2] * inv);
                pk.h4[3] = __float2bfloat16(o[u][t][3] * inv);
                *(uint2*)(orow + t * 16 + lq * 4) = pk.v;
            }
        }
    } else {
        // split: write unnormalized bf16 partial O + fp32 l
        const long pbase = ((long)(b * 32 + h) * 16 + pidx) * (128 * 64);
        const long lbase = ((long)(b * 32 + h) * 16 + pidx) * 128;
        for (int u = 0; u < 2; ++u) {
            lrow[u] += __shfl_xor(lrow[u], 16);
            lrow[u] += __shfl_xor(lrow[u], 32);
            const int qq = wave * 32 + u * 16 + lm;
            if (lq == 0) Lbuf[lbase + qq] = lrow[u];
            bf16* prow = Pbuf + pbase + (long)qq * 64;
            for (int t = 0; t < 4; ++t) {
                union { bf16 h4[4]; uint2 v; } pk;
                pk.h4[0] = __float2bfloat16(o[u][t][0]);
                pk.h4[1] = __float2bfloat16(o[u][t][1]);
                pk.h4[2] = __float2bfloat16(o[u][t][2]);
                pk.h4[3] = __float2bfloat16(o[u][t][3]);
                *(uint2*)(prow + t * 16 + lq * 4) = pk.v;
            }
        }
    }
}

// Combine split partials: O = (p0+p1)/(l0+l1) for tokens with qblk >= 8.
__global__ void attn_combine(const bf16* __restrict__ Pbuf, const float* __restrict__ Lbuf,
                             bf16* __restrict__ O) {
    int gid = blockIdx.x * 256 + threadIdx.x;      // 2*1024*32*16 threads
    int d4 = gid & 15;
    int h  = (gid >> 4) & 31;
    int qt = (gid >> 9) & 1023;                    // token - 1024
    int b  = gid >> 19;
    int q  = 1024 + qt;
    int qblk = q >> 7;                             // 8..15
    int qq = q & 127;
    long base = ((long)(b * 32 + h) * 16 + (qblk - 8) * 2);
    const bf16* p0 = Pbuf + base * (128 * 64) + qq * 64 + d4 * 4;
    const bf16* p1 = p0 + 128 * 64;
    float l = Lbuf[base * 128 + qq] + Lbuf[base * 128 + 128 + qq];
    float inv = 1.0f / l;
    union { bf16 h4[4]; uint2 v; } a, c, w;
    a.v = *(const uint2*)p0;
    c.v = *(const uint2*)p1;
    for (int i = 0; i < 4; ++i)
        w.h4[i] = __float2bfloat16((__bfloat162float(a.h4[i]) + __bfloat162float(c.h4[i])) * inv);
    *(uint2*)(O + ((long)(b * cS + q) * cNH + h) * cDH + d4 * 4) = w.v;
}

// ---------------------------------------------------------------------------
// launcher
// ---------------------------------------------------------------------------
extern "C" void kernel_launch(void* const* d_in, const int* in_sizes, int n_in,
                              void* d_out, int out_size, void* d_ws, size_t ws_size,
                              hipStream_t stream) {
    const float* hs  = (const float*)d_in[0];
    const int*   pos = (const int*)d_in[1];
    const float* Wq  = (const float*)d_in[2];
    const float* Wk  = (const float*)d_in[3];
    const float* Wv  = (const float*)d_in[4];
    const float* Wo  = (const float*)d_in[5];
    float* out = (float*)d_out;
    char* ws = (char*)d_ws;

    // workspace layout (bytes)
    bf16* hsb = (bf16*)(ws + 0);              // [4096][2048]        16.78 MB
    bf16* WT  = (bf16*)(ws + 16777216);       // [3072][2048] fused QKV^T 12.58 MB
    bf16* WoT = (bf16*)(ws + 29360128);       // [2048][2048]         8.39 MB
    bf16* QKV = (bf16*)(ws + 37748736);       // [4096][3072]        25.17 MB
    bf16* VTb = (bf16*)(ws + 62914560);       // [2][8][64][2048]     4.19 MB
    bf16* AOb = (bf16*)(ws + 67108864);       // [4096][2048]        16.78 MB
    // attention partial buffers REUSE the hsb/WT region (dead after QKV gemm):
    bf16* Pbuf = (bf16*)(ws + 0);             // 64bh x 16 x 128q x 64d bf16  16.78 MB
    float* Lbuf = (float*)(ws + 20971520);    // 64bh x 16 x 128q fp32        0.52 MB
    // total 83.9 MB

    dim3 tb(32, 8);

    // 1) hs -> bf16
    cvt_f32_bf16<<<8192, 256, 0, stream>>>(hs, hsb, (cB * cS * cH) / 4);
    // 2) weights -> fused B^T bf16 (rows: 0..2047 Wq, 2048..2559 Wk, 2560..3071 Wv)
    transpose_f32_bf16<<<dim3(64, 64), tb, 0, stream>>>(Wq, WT, 2048, 2048);
    transpose_f32_bf16<<<dim3(16, 64), tb, 0, stream>>>(Wk, WT + 2048 * 2048, 2048, 512);
    transpose_f32_bf16<<<dim3(16, 64), tb, 0, stream>>>(Wv, WT + 2560 * 2048, 2048, 512);
    transpose_f32_bf16<<<dim3(64, 64), tb, 0, stream>>>(Wo, WoT, 2048, 2048);
    // 3) fused QKV projection: [4096][3072] = hsb @ WT^T
    gemm_bt<bf16><<<dim3(32, 24), 256, 0, stream>>>(hsb, WT, QKV, 4096, cQKVW, 2048);
    // 4) RoPE in place on K only (Q-RoPE fused into attention)
    rope_kernel<<<4096, 256, 0, stream>>>(QKV + 2048, pos, 8, 3, cQKVW, 4096 * 8 * 32);
    // 5) V (cols 2560..3071) -> VT
    transpose_v<<<dim3(2, 64, 16), tb, 0, stream>>>(QKV + 2560, VTb);
    // 6) attention: 24 units x 64 (b,h); heavy-first, key-split for qblk>=8
    attn_kernel<<<1536, 256, 0, stream>>>(QKV, VTb, pos, AOb, Pbuf, Lbuf);
    // 6b) combine split partials into AOb (tokens 1024..2047 per batch)
    attn_combine<<<4096, 256, 0, stream>>>(Pbuf, Lbuf, AOb);
    // 7) output projection -> fp32 d_out
    gemm_bt<float><<<dim3(32, 16), 256, 0, stream>>>(AOb, WoT, out, 4096, 2048, 2048);
}